// Round 24
// baseline (34.740 us; speedup 1.0000x reference)
//
#include <hip/hip_runtime.h>
#include <hip/hip_bf16.h>

#define IMAGE_SIZE 416
#define DECODED 64
#define NPIX (IMAGE_SIZE * IMAGE_SIZE)   // 173056
#define D_IN 64
#define H1 512
#define OUT2 12288                       // 3*64*64

typedef short bf16x8 __attribute__((ext_vector_type(8)));
typedef float f32x4 __attribute__((ext_vector_type(4)));

__device__ __forceinline__ short f2bf(float f) {   // RNE f32->bf16
    union { float f; unsigned u; } x; x.f = f;
    unsigned r = x.u + 0x7FFFu + ((x.u >> 16) & 1u);
    return (short)(r >> 16);
}

// ---------------- Kernel 1: front = mlp1-bf16 (blocks 0..127) + wts (128) ---
// mlp1 writes the A-operand directly in MFMA fragment order (a_pk, 128 KB).
__global__ __launch_bounds__(512) void front_kernel(const float* __restrict__ z_what,
                                                    const float* __restrict__ w1,
                                                    const float* __restrict__ b1,
                                                    const float* __restrict__ z_where,
                                                    const int* __restrict__ z_present,
                                                    const float* __restrict__ z_depth,
                                                    short* __restrict__ a_pk,
                                                    float* __restrict__ pobj,
                                                    int* __restrict__ pcnt) {
    const int bx = blockIdx.x;
    const int t = threadIdx.x;
    const int lane = t & 63;
    const int wv = t >> 6;

    const int p = (t < 128) ? z_present[t] : 0;
    const unsigned long long bal = __ballot(p != 0);
    __shared__ unsigned long long smask[8];
    __shared__ int sorig;
    if (lane == 0) smask[wv] = bal;
    if (t == 0) sorig = -1;
    __syncthreads();
    const unsigned long long m0 = smask[0];
    const unsigned long long m1 = smask[1];
    const int cnt0 = __popcll(m0);
    const unsigned long long below =
        (wv == 0 ? m0 : m1) & ((lane ? ((1ull << lane) - 1) : 0ull));
    const int gslot = (wv == 0 ? 0 : cnt0) + __popcll(below);

    if (bx == 128) {
        __shared__ float sd[128];
        __shared__ float se[128];
        float d = 0.0f;
        if (t < 128) {
            d = p ? z_depth[t] : -1000.0f;
            sd[t] = d;
        }
        __syncthreads();
        float e = 0.0f;
        if (t < 128) {
            const int b = t >> 5;
            float m = -1e30f;
#pragma unroll
            for (int k = 0; k < 32; ++k) m = fmaxf(m, sd[(b << 5) + k]);
            e = expf(d - m);
            se[t] = e;
        }
        __syncthreads();
        if (t < 128) {
            const int b = t >> 5;
            float s = 0.0f;
#pragma unroll
            for (int k = 0; k < 32; ++k) s += se[(b << 5) + k];
            const float wgt = p ? (e / s) : 0.0f;

            const unsigned bb32 =
                (unsigned)(((wv == 0 ? m0 : m1) >> (t & 32)) & 0xFFFFFFFFull);
            const int lb = t & 31;
            const int mb = __popc(bb32 & (lb ? ((1u << lb) - 1u) : 0u));
            const int cnt_b = __popc(bb32);
            if (lb == 0) pcnt[b] = cnt_b;

            if (p) {
                const float xc = z_where[t * 4 + 0];
                const float yc = z_where[t * 4 + 1];
                const float ww = z_where[t * 4 + 2];
                const float hh = z_where[t * 4 + 3];
                float* o = pobj + (size_t)(b * 32 + mb) * 8;
                o[0] = 2.0f * xc - 1.0f;
                o[1] = 2.0f * yc - 1.0f;
                o[2] = 1.0f / fmaxf(ww, 0.001f);
                o[3] = 1.0f / fmaxf(hh, 0.001f);
                o[4] = wgt;
                o[5] = (float)gslot;
                o[6] = 0.0f; o[7] = 0.0f;
            }
        }
        return;
    }

    // mlp1 path: compact slot bx -> orig row via ballot; bx >= count -> zeros
    if (t < 128 && p && gslot == bx) sorig = t;
    __syncthreads();
    const int orig = sorig;                 // -1 when bx >= count

    const int h = t;                        // k index 0..511
    float val = 0.0f;
    if (orig >= 0) {
        const float* zr = z_what + orig * D_IN;   // uniform -> scalar loads
        float acc = b1[h];
#pragma unroll
        for (int d = 0; d < D_IN; ++d)
            acc = fmaf(zr[d], w1[d * H1 + h], acc);
        val = fmaxf(acc, 0.0f);
    }
    // fragment-packed store: row = bx, k = h
    const int S  = h >> 5;
    const int g  = (h >> 3) & 3;
    const int i  = h & 7;
    const int mt = bx >> 4;
    const int c  = bx & 15;
    a_pk[(((S * 8 + mt) * 64) + g * 16 + c) * 8 + i] = f2bf(val);
}

// ---------------- Kernel 1b: conv = pack bf16(w2) in B-fragment order -------
// b_pk[S][nt][l][i]: S = k>>5 (0..15), nt = col-tile (0..767, 16 cols),
// lane l: col = nt*16 + (l&15), k = S*32 + (l>>4)*8 + i. 12 MB bf16.
// Pure streaming gather (each 64-B w2 line read exactly once, 3072 blocks
// -> ~48 waves/CU of TLP, no compute dependency) + perfectly coalesced
// 16B/lane writes. Moves the strided B-access OUT of the MFMA dependency
// chain — the same mechanism as R18's A-packing (-5.1 us).
__global__ __launch_bounds__(256) void conv_kernel(const float* __restrict__ w2,
                                                   short* __restrict__ b_pk) {
    const int gid = blockIdx.x * 256 + threadIdx.x;   // 0..786431
    const int l = gid & 63;
    const int f = gid >> 6;                           // 0..12287 = S*768+nt
    const int S = f / 768;
    const int nt = f - S * 768;
    const int k0 = S * 32 + (l >> 4) * 8;
    const int col = nt * 16 + (l & 15);
    const float* src = w2 + (size_t)k0 * OUT2 + col;
    bf16x8 v;
#pragma unroll
    for (int i = 0; i < 8; ++i) v[i] = f2bf(src[(size_t)i * OUT2]);
    *(bf16x8*)(b_pk + (size_t)gid * 8) = v;
}

// ---------------- Kernel 2: dec = sigmoid(A @ B + b2) via MFMA ---------------
// Grid 384 blocks x 256 thr (4 waves = 4 K-chunks of 128); block owns 32
// cols (two 16-col fragments). BOTH operands now load as one coalesced
// 16B/lane instruction per fragment from packed layouts (a_pk, b_pk).
// One-round 48 KB LDS reduce; wave 0 fuses bias+sigmoid+store.
// Fragment maps (R13-verified): B lane l: col=l&15, k=(l>>4)*8+i.
//   D lane l: col=l&15, row=(l>>4)*4+reg.
__global__ __launch_bounds__(256, 3) void mlp2_mfma(const short* __restrict__ a_pk,
                                                    const short* __restrict__ b_pk,
                                                    const float* __restrict__ b2,
                                                    float* __restrict__ dec) {
    const int strip = blockIdx.x;            // 0..383 -> cols [strip*32, +32)
    const int tid = threadIdx.x;
    const int kg  = tid >> 6;                // wave = K-chunk 0..3
    const int l   = tid & 63;
    const int l15 = l & 15;
    const int g   = l >> 4;                  // 0..3
    const int n0  = strip * 32 + l15;        // j=0 column; j=1 column = n0+16

    f32x4 acc0[8], acc1[8];
#pragma unroll
    for (int q = 0; q < 8; ++q) {
        acc0[q] = (f32x4){0.f, 0.f, 0.f, 0.f};
        acc1[q] = (f32x4){0.f, 0.f, 0.f, 0.f};
    }

#pragma unroll
    for (int ks = 0; ks < 4; ++ks) {
        const int S = kg * 4 + ks;           // k-step of 32
        // B fragments: coalesced 16B/lane from packed layout
        const bf16x8 b0 = *(const bf16x8*)(b_pk +
            (size_t)((S * 768 + strip * 2) * 64 + l) * 8);
        const bf16x8 b1 = *(const bf16x8*)(b_pk +
            (size_t)((S * 768 + strip * 2 + 1) * 64 + l) * 8);

        const short* ab = a_pk + (size_t)S * 4096 + l * 8;
#pragma unroll
        for (int q = 0; q < 8; ++q) {
            const bf16x8 a = *(const bf16x8*)(ab + (size_t)q * 512);
            acc0[q] = __builtin_amdgcn_mfma_f32_16x16x32_bf16(a, b0, acc0[q], 0, 0, 0);
            acc1[q] = __builtin_amdgcn_mfma_f32_16x16x32_bf16(a, b1, acc1[q], 0, 0, 0);
        }
    }

    // ---- one-round LDS reduce: waves 1..3 write, wave 0 sums ----
    __shared__ f32x4 red[3][16][64];         // 48 KB
    if (kg > 0) {
#pragma unroll
        for (int q = 0; q < 8; ++q) {
            red[kg - 1][q][l] = acc0[q];
            red[kg - 1][q + 8][l] = acc1[q];
        }
    }
    __syncthreads();
    if (kg == 0) {
        const float bb0 = b2[n0];
        const float bb1 = b2[n0 + 16];
#pragma unroll
        for (int q = 0; q < 8; ++q) {
            const f32x4 p00 = red[0][q][l];
            const f32x4 p01 = red[1][q][l];
            const f32x4 p02 = red[2][q][l];
            const f32x4 p10 = red[0][q + 8][l];
            const f32x4 p11 = red[1][q + 8][l];
            const f32x4 p12 = red[2][q + 8][l];
#pragma unroll
            for (int r = 0; r < 4; ++r) {
                const int m = q * 16 + g * 4 + r;       // D row mapping
                const float x0 = acc0[q][r] + p00[r] + p01[r] + p02[r] + bb0;
                const float x1 = acc1[q][r] + p10[r] + p11[r] + p12[r] + bb1;
                dec[(size_t)m * OUT2 + n0]      = 1.0f / (1.0f + __expf(-x0));
                dec[(size_t)m * OUT2 + n0 + 16] = 1.0f / (1.0f + __expf(-x1));
            }
        }
    }
}

// ---------------- Kernel 3: composite, per-block culled object list ---------
__global__ __launch_bounds__(256) void composite_kernel(const float* __restrict__ dec,
                                                        const float* __restrict__ pobj,
                                                        const int* __restrict__ pcnt,
                                                        float* __restrict__ out) {
    const int tx = threadIdx.x & 31;
    const int ty = threadIdx.x >> 5;
    const int w = blockIdx.x * 32 + tx;      // 13*32 = 416
    const int h = blockIdx.y * 8 + ty;       // 52*8  = 416
    const int b = blockIdx.z;

    __shared__ float slist[32 * 8];
    __shared__ int scount;

    if (threadIdx.x < 64) {
        const int cb = min(max(pcnt[b], 0), 32);
        const float* po = pobj + (size_t)b * 32 * 8;
        const float u0 = fmaf((float)(blockIdx.x * 32), 2.0f / 415.0f, -1.0f);
        const float u1 = fmaf((float)(blockIdx.x * 32 + 31), 2.0f / 415.0f, -1.0f);
        const float v0 = fmaf((float)(blockIdx.y * 8), 2.0f / 415.0f, -1.0f);
        const float v1 = fmaf((float)(blockIdx.y * 8 + 7), 2.0f / 415.0f, -1.0f);

        const int l = threadIdx.x;           // lane 0..63; objects on lanes < cb
        float4 A = make_float4(0.f, 0.f, 0.f, 0.f);
        float4 B = make_float4(0.f, 0.f, 0.f, 0.f);
        bool keep = false;
        if (l < cb) {
            A = *(const float4*)(po + l * 8);
            B = *(const float4*)(po + l * 8 + 4);
            const float pxlo = ((u0 - A.x) * A.z + 1.0f) * 31.5f;
            const float pxhi = ((u1 - A.x) * A.z + 1.0f) * 31.5f;
            const float pylo = ((v0 - A.y) * A.w + 1.0f) * 31.5f;
            const float pyhi = ((v1 - A.y) * A.w + 1.0f) * 31.5f;
            keep = !(pxhi <= -1.0f || pxlo >= (float)DECODED ||
                     pyhi <= -1.0f || pylo >= (float)DECODED);
        }
        const unsigned long long mask = __ballot(keep);
        if (keep) {
            const int pos = __popcll(mask & ((l ? ((1ull << l) - 1) : 0ull)));
            float* s = slist + pos * 8;
            *(float4*)s = A;
            *(float4*)(s + 4) = B;
        }
        if (l == 0) scount = (int)__popcll(mask);
    }
    __syncthreads();

    const int nk = scount;
    const float u = fmaf((float)w, 2.0f / 415.0f, -1.0f);
    const float v = fmaf((float)h, 2.0f / 415.0f, -1.0f);

    float a0 = 0.0f, a1 = 0.0f, a2 = 0.0f;

    for (int m_ = 0; m_ < nk; ++m_) {
        const float4 A = *(const float4*)(slist + m_ * 8);    // LDS broadcast
        const float4 B = *(const float4*)(slist + m_ * 8 + 4);
        const float gx = (u - A.x) * A.z;
        const float gy = (v - A.y) * A.w;
        const float px = (gx + 1.0f) * (0.5f * (DECODED - 1));
        const float py = (gy + 1.0f) * (0.5f * (DECODED - 1));
        if (px <= -1.0f || px >= (float)DECODED || py <= -1.0f || py >= (float)DECODED)
            continue;

        const float x0f = floorf(px), y0f = floorf(py);
        const int x0 = (int)x0f, y0 = (int)y0f;
        const float wx1 = px - x0f, wx0 = 1.0f - wx1;
        const float wy1 = py - y0f, wy0 = 1.0f - wy1;

        const bool vx0 = (x0 >= 0) & (x0 <= DECODED - 1);
        const bool vx1 = (x0 + 1 >= 0) & (x0 + 1 <= DECODED - 1);
        const bool vy0 = (y0 >= 0) & (y0 <= DECODED - 1);
        const bool vy1 = (y0 + 1 >= 0) & (y0 + 1 <= DECODED - 1);

        const int xc0 = min(max(x0, 0), DECODED - 1);
        const int xc1 = min(max(x0 + 1, 0), DECODED - 1);
        const int yc0 = min(max(y0, 0), DECODED - 1);
        const int yc1 = min(max(y0 + 1, 0), DECODED - 1);

        const float w00 = wx0 * wy0 * (float)(vx0 && vy0);
        const float w10 = wx1 * wy0 * (float)(vx1 && vy0);
        const float w01 = wx0 * wy1 * (float)(vx0 && vy1);
        const float w11 = wx1 * wy1 * (float)(vx1 && vy1);

        const int slot = min(max((int)B.y, 0), 127);
        const float wgt = B.x;
        const float* base = dec + (size_t)slot * OUT2;
        const int i00 = yc0 * DECODED + xc0;
        const int i10 = yc0 * DECODED + xc1;
        const int i01 = yc1 * DECODED + xc0;
        const int i11 = yc1 * DECODED + xc1;

        {
            const float* pp = base;
            float gg = w00 * pp[i00] + w10 * pp[i10] + w01 * pp[i01] + w11 * pp[i11];
            a0 = fmaf(wgt, gg, a0);
        }
        {
            const float* pp = base + 4096;
            float gg = w00 * pp[i00] + w10 * pp[i10] + w01 * pp[i01] + w11 * pp[i11];
            a1 = fmaf(wgt, gg, a1);
        }
        {
            const float* pp = base + 8192;
            float gg = w00 * pp[i00] + w10 * pp[i10] + w01 * pp[i01] + w11 * pp[i11];
            a2 = fmaf(wgt, gg, a2);
        }
    }

    out[((size_t)(b * 3 + 0) * IMAGE_SIZE + h) * IMAGE_SIZE + w] = a0;
    out[((size_t)(b * 3 + 1) * IMAGE_SIZE + h) * IMAGE_SIZE + w] = a1;
    out[((size_t)(b * 3 + 2) * IMAGE_SIZE + h) * IMAGE_SIZE + w] = a2;
}

extern "C" void kernel_launch(void* const* d_in, const int* in_sizes, int n_in,
                              void* d_out, int out_size, void* d_ws, size_t ws_size,
                              hipStream_t stream) {
    const float* z_where   = (const float*)d_in[0];   // [4,32,4]
    const int*   z_present = (const int*)d_in[1];     // [4,32,1]
    const float* z_what    = (const float*)d_in[2];   // [4,32,64]
    const float* z_depth   = (const float*)d_in[3];   // [4,32,1]
    const float* w1 = (const float*)d_in[4];          // [64,512]
    const float* b1 = (const float*)d_in[5];          // [512]
    const float* w2 = (const float*)d_in[6];          // [512,12288]
    const float* b2 = (const float*)d_in[7];          // [12288]
    float* out = (float*)d_out;                       // [4,3,416,416] f32

    char* ws = (char*)d_ws;
    float* dec  = (float*)ws;                         //  6,291,456 B
    short* a_pk = (short*)(ws + 6291456);             //    131,072 B
    short* b_pk = (short*)(ws + 6422528);             // 12,582,912 B
    float* pobj = (float*)(ws + 19005440);            //      4,096 B
    int*  pcnt  = (int*)(ws + 19009536);              //        256 B
    const size_t ws_needed = 19009792;

    if (ws_size >= ws_needed) {
        front_kernel<<<129, 512, 0, stream>>>(z_what, w1, b1, z_where, z_present,
                                              z_depth, a_pk, pobj, pcnt);
        conv_kernel<<<3072, 256, 0, stream>>>(w2, b_pk);
        mlp2_mfma<<<384, 256, 0, stream>>>(a_pk, b_pk, b2, dec);
        composite_kernel<<<dim3(13, 52, 4), 256, 0, stream>>>(dec, pobj, pcnt, out);
    } else {
        // should not happen (R5 established ws >= 31 MB); conservative no-op
        // fallback: reuse conv into a smaller region is impossible -> run
        // the packed-A path with strided B by aliasing b_pk over dec is NOT
        // safe; instead run conv into dec's space first, then GEMM, then
        // composite would clobber... keep it simple: full path requires ws.
        front_kernel<<<129, 512, 0, stream>>>(z_what, w1, b1, z_where, z_present,
                                              z_depth, a_pk, pobj, pcnt);
        conv_kernel<<<3072, 256, 0, stream>>>(w2, b_pk);
        mlp2_mfma<<<384, 256, 0, stream>>>(a_pk, b_pk, b2, dec);
        composite_kernel<<<dim3(13, 52, 4), 256, 0, stream>>>(dec, pobj, pcnt, out);
    }
}

// Round 25
// 29.275 us; speedup vs baseline: 1.1867x; 1.1867x over previous
//
#include <hip/hip_runtime.h>
#include <hip/hip_bf16.h>

#define IMAGE_SIZE 416
#define DECODED 64
#define NPIX (IMAGE_SIZE * IMAGE_SIZE)   // 173056
#define D_IN 64
#define H1 512
#define OUT2 12288                       // 3*64*64

typedef short bf16x8 __attribute__((ext_vector_type(8)));
typedef float f32x4 __attribute__((ext_vector_type(4)));

__device__ __forceinline__ short f2bf(float f) {   // RNE f32->bf16
    union { float f; unsigned u; } x; x.f = f;
    unsigned r = x.u + 0x7FFFu + ((x.u >> 16) & 1u);
    return (short)(r >> 16);
}

// ---------------- Kernel 1: front = mlp1-bf16 (blocks 0..127) + wts (128) ---
// mlp1 writes the A-operand directly in MFMA fragment order (a_pk, 128 KB).
// Rows >= count zeroed. pobj per (batch,local-slot):
//   tx, ty, inv_sx, inv_sy, weight, global_slot, 0, 0. pcnt[b] = #present.
__global__ __launch_bounds__(512) void front_kernel(const float* __restrict__ z_what,
                                                    const float* __restrict__ w1,
                                                    const float* __restrict__ b1,
                                                    const float* __restrict__ z_where,
                                                    const int* __restrict__ z_present,
                                                    const float* __restrict__ z_depth,
                                                    short* __restrict__ a_pk,
                                                    float* __restrict__ pobj,
                                                    int* __restrict__ pcnt) {
    const int bx = blockIdx.x;
    const int t = threadIdx.x;
    const int lane = t & 63;
    const int wv = t >> 6;

    const int p = (t < 128) ? z_present[t] : 0;
    const unsigned long long bal = __ballot(p != 0);
    __shared__ unsigned long long smask[8];
    __shared__ int sorig;
    if (lane == 0) smask[wv] = bal;
    if (t == 0) sorig = -1;
    __syncthreads();
    const unsigned long long m0 = smask[0];
    const unsigned long long m1 = smask[1];
    const int cnt0 = __popcll(m0);
    const unsigned long long below =
        (wv == 0 ? m0 : m1) & ((lane ? ((1ull << lane) - 1) : 0ull));
    const int gslot = (wv == 0 ? 0 : cnt0) + __popcll(below);

    if (bx == 128) {
        __shared__ float sd[128];
        __shared__ float se[128];
        float d = 0.0f;
        if (t < 128) {
            d = p ? z_depth[t] : -1000.0f;
            sd[t] = d;
        }
        __syncthreads();
        float e = 0.0f;
        if (t < 128) {
            const int b = t >> 5;
            float m = -1e30f;
#pragma unroll
            for (int k = 0; k < 32; ++k) m = fmaxf(m, sd[(b << 5) + k]);
            e = expf(d - m);
            se[t] = e;
        }
        __syncthreads();
        if (t < 128) {
            const int b = t >> 5;
            float s = 0.0f;
#pragma unroll
            for (int k = 0; k < 32; ++k) s += se[(b << 5) + k];
            const float wgt = p ? (e / s) : 0.0f;

            const unsigned bb32 =
                (unsigned)(((wv == 0 ? m0 : m1) >> (t & 32)) & 0xFFFFFFFFull);
            const int lb = t & 31;
            const int mb = __popc(bb32 & (lb ? ((1u << lb) - 1u) : 0u));
            const int cnt_b = __popc(bb32);
            if (lb == 0) pcnt[b] = cnt_b;

            if (p) {
                const float xc = z_where[t * 4 + 0];
                const float yc = z_where[t * 4 + 1];
                const float ww = z_where[t * 4 + 2];
                const float hh = z_where[t * 4 + 3];
                float* o = pobj + (size_t)(b * 32 + mb) * 8;
                o[0] = 2.0f * xc - 1.0f;
                o[1] = 2.0f * yc - 1.0f;
                o[2] = 1.0f / fmaxf(ww, 0.001f);
                o[3] = 1.0f / fmaxf(hh, 0.001f);
                o[4] = wgt;
                o[5] = (float)gslot;
                o[6] = 0.0f; o[7] = 0.0f;
            }
        }
        return;
    }

    // mlp1 path: compact slot bx -> orig row via ballot; bx >= count -> zeros
    if (t < 128 && p && gslot == bx) sorig = t;
    __syncthreads();
    const int orig = sorig;                 // -1 when bx >= count

    const int h = t;                        // k index 0..511
    float val = 0.0f;
    if (orig >= 0) {
        const float* zr = z_what + orig * D_IN;   // uniform -> scalar loads
        float acc = b1[h];
#pragma unroll
        for (int d = 0; d < D_IN; ++d)
            acc = fmaf(zr[d], w1[d * H1 + h], acc);
        val = fmaxf(acc, 0.0f);
    }
    // fragment-packed store: row = bx, k = h
    const int S  = h >> 5;
    const int g  = (h >> 3) & 3;
    const int i  = h & 7;
    const int mt = bx >> 4;
    const int c  = bx & 15;
    a_pk[(((S * 8 + mt) * 64) + g * 16 + c) * 8 + i] = f2bf(val);
}

// ---------------- Kernel 2: dec = sigmoid(A @ bf16(w2) + b2) via MFMA --------
// Grid 384 blocks x 256 thr (4 waves = 4 K-chunks of 128); each block owns
// 32 columns (two 16-col fragments b0,b1 sharing each A fragment): halves
// a_pk L2-amplification and makes paired b0/b1 loads touch both halves of
// each 128-B w2 line in one wave. A-frags: coalesced 16B/lane from the
// fragment-packed a_pk (R18: -5.1 us vs row-scatter). w2 read from HBM/L3
// exactly once as f32 + in-register RNE convert (B-packing via a separate
// kernel was tried in R24 and regressed: the round-trip cost > GEMM gain).
// One-round 48 KB LDS reduce; wave 0 fuses bias+sigmoid+store.
// Fragment maps (R13-verified): B lane l: col=l&15, k=(l>>4)*8+i.
//   D lane l: col=l&15, row=(l>>4)*4+reg.
__global__ __launch_bounds__(256, 3) void mlp2_mfma(const short* __restrict__ a_pk,
                                                    const float* __restrict__ w2,
                                                    const float* __restrict__ b2,
                                                    float* __restrict__ dec) {
    const int strip = blockIdx.x;            // 0..383 -> cols [strip*32, +32)
    const int tid = threadIdx.x;
    const int kg  = tid >> 6;                // wave = K-chunk 0..3
    const int l   = tid & 63;
    const int l15 = l & 15;
    const int g   = l >> 4;                  // 0..3
    const int n0  = strip * 32 + l15;        // j=0 column; j=1 column = n0+16

    f32x4 acc0[8], acc1[8];
#pragma unroll
    for (int q = 0; q < 8; ++q) {
        acc0[q] = (f32x4){0.f, 0.f, 0.f, 0.f};
        acc1[q] = (f32x4){0.f, 0.f, 0.f, 0.f};
    }

#pragma unroll
    for (int ks = 0; ks < 4; ++ks) {
        const int S = kg * 4 + ks;           // k-step of 32
        const float* wp = w2 + (size_t)(S * 32 + g * 8) * OUT2 + n0;
        float bt0[8], bt1[8];
#pragma unroll
        for (int i = 0; i < 8; ++i) {
            bt0[i] = wp[(size_t)i * OUT2];
            bt1[i] = wp[(size_t)i * OUT2 + 16];
        }
        bf16x8 b0, b1;
#pragma unroll
        for (int i = 0; i < 8; ++i) { b0[i] = f2bf(bt0[i]); b1[i] = f2bf(bt1[i]); }

        const short* ab = a_pk + (size_t)S * 4096 + l * 8;
#pragma unroll
        for (int q = 0; q < 8; ++q) {
            const bf16x8 a = *(const bf16x8*)(ab + (size_t)q * 512);
            acc0[q] = __builtin_amdgcn_mfma_f32_16x16x32_bf16(a, b0, acc0[q], 0, 0, 0);
            acc1[q] = __builtin_amdgcn_mfma_f32_16x16x32_bf16(a, b1, acc1[q], 0, 0, 0);
        }
    }

    // ---- one-round LDS reduce: waves 1..3 write, wave 0 sums ----
    __shared__ f32x4 red[3][16][64];         // 48 KB
    if (kg > 0) {
#pragma unroll
        for (int q = 0; q < 8; ++q) {
            red[kg - 1][q][l] = acc0[q];
            red[kg - 1][q + 8][l] = acc1[q];
        }
    }
    __syncthreads();
    if (kg == 0) {
        const float bb0 = b2[n0];
        const float bb1 = b2[n0 + 16];
#pragma unroll
        for (int q = 0; q < 8; ++q) {
            const f32x4 p00 = red[0][q][l];
            const f32x4 p01 = red[1][q][l];
            const f32x4 p02 = red[2][q][l];
            const f32x4 p10 = red[0][q + 8][l];
            const f32x4 p11 = red[1][q + 8][l];
            const f32x4 p12 = red[2][q + 8][l];
#pragma unroll
            for (int r = 0; r < 4; ++r) {
                const int m = q * 16 + g * 4 + r;       // D row mapping
                const float x0 = acc0[q][r] + p00[r] + p01[r] + p02[r] + bb0;
                const float x1 = acc1[q][r] + p10[r] + p11[r] + p12[r] + bb1;
                dec[(size_t)m * OUT2 + n0]      = 1.0f / (1.0f + __expf(-x0));
                dec[(size_t)m * OUT2 + n0 + 16] = 1.0f / (1.0f + __expf(-x1));
            }
        }
    }
}

// ---------------- Kernel 3: composite, per-block culled object list ---------
__global__ __launch_bounds__(256) void composite_kernel(const float* __restrict__ dec,
                                                        const float* __restrict__ pobj,
                                                        const int* __restrict__ pcnt,
                                                        float* __restrict__ out) {
    const int tx = threadIdx.x & 31;
    const int ty = threadIdx.x >> 5;
    const int w = blockIdx.x * 32 + tx;      // 13*32 = 416
    const int h = blockIdx.y * 8 + ty;       // 52*8  = 416
    const int b = blockIdx.z;

    __shared__ float slist[32 * 8];
    __shared__ int scount;

    if (threadIdx.x < 64) {
        const int cb = min(max(pcnt[b], 0), 32);
        const float* po = pobj + (size_t)b * 32 * 8;
        const float u0 = fmaf((float)(blockIdx.x * 32), 2.0f / 415.0f, -1.0f);
        const float u1 = fmaf((float)(blockIdx.x * 32 + 31), 2.0f / 415.0f, -1.0f);
        const float v0 = fmaf((float)(blockIdx.y * 8), 2.0f / 415.0f, -1.0f);
        const float v1 = fmaf((float)(blockIdx.y * 8 + 7), 2.0f / 415.0f, -1.0f);

        const int l = threadIdx.x;           // lane 0..63; objects on lanes < cb
        float4 A = make_float4(0.f, 0.f, 0.f, 0.f);
        float4 B = make_float4(0.f, 0.f, 0.f, 0.f);
        bool keep = false;
        if (l < cb) {
            A = *(const float4*)(po + l * 8);
            B = *(const float4*)(po + l * 8 + 4);
            const float pxlo = ((u0 - A.x) * A.z + 1.0f) * 31.5f;
            const float pxhi = ((u1 - A.x) * A.z + 1.0f) * 31.5f;
            const float pylo = ((v0 - A.y) * A.w + 1.0f) * 31.5f;
            const float pyhi = ((v1 - A.y) * A.w + 1.0f) * 31.5f;
            keep = !(pxhi <= -1.0f || pxlo >= (float)DECODED ||
                     pyhi <= -1.0f || pylo >= (float)DECODED);
        }
        const unsigned long long mask = __ballot(keep);
        if (keep) {
            const int pos = __popcll(mask & ((l ? ((1ull << l) - 1) : 0ull)));
            float* s = slist + pos * 8;
            *(float4*)s = A;
            *(float4*)(s + 4) = B;
        }
        if (l == 0) scount = (int)__popcll(mask);
    }
    __syncthreads();

    const int nk = scount;
    const float u = fmaf((float)w, 2.0f / 415.0f, -1.0f);
    const float v = fmaf((float)h, 2.0f / 415.0f, -1.0f);

    float a0 = 0.0f, a1 = 0.0f, a2 = 0.0f;

    for (int m_ = 0; m_ < nk; ++m_) {
        const float4 A = *(const float4*)(slist + m_ * 8);    // LDS broadcast
        const float4 B = *(const float4*)(slist + m_ * 8 + 4);
        const float gx = (u - A.x) * A.z;
        const float gy = (v - A.y) * A.w;
        const float px = (gx + 1.0f) * (0.5f * (DECODED - 1));
        const float py = (gy + 1.0f) * (0.5f * (DECODED - 1));
        if (px <= -1.0f || px >= (float)DECODED || py <= -1.0f || py >= (float)DECODED)
            continue;

        const float x0f = floorf(px), y0f = floorf(py);
        const int x0 = (int)x0f, y0 = (int)y0f;
        const float wx1 = px - x0f, wx0 = 1.0f - wx1;
        const float wy1 = py - y0f, wy0 = 1.0f - wy1;

        const bool vx0 = (x0 >= 0) & (x0 <= DECODED - 1);
        const bool vx1 = (x0 + 1 >= 0) & (x0 + 1 <= DECODED - 1);
        const bool vy0 = (y0 >= 0) & (y0 <= DECODED - 1);
        const bool vy1 = (y0 + 1 >= 0) & (y0 + 1 <= DECODED - 1);

        const int xc0 = min(max(x0, 0), DECODED - 1);
        const int xc1 = min(max(x0 + 1, 0), DECODED - 1);
        const int yc0 = min(max(y0, 0), DECODED - 1);
        const int yc1 = min(max(y0 + 1, 0), DECODED - 1);

        const float w00 = wx0 * wy0 * (float)(vx0 && vy0);
        const float w10 = wx1 * wy0 * (float)(vx1 && vy0);
        const float w01 = wx0 * wy1 * (float)(vx0 && vy1);
        const float w11 = wx1 * wy1 * (float)(vx1 && vy1);

        const int slot = min(max((int)B.y, 0), 127);
        const float wgt = B.x;
        const float* base = dec + (size_t)slot * OUT2;
        const int i00 = yc0 * DECODED + xc0;
        const int i10 = yc0 * DECODED + xc1;
        const int i01 = yc1 * DECODED + xc0;
        const int i11 = yc1 * DECODED + xc1;

        {
            const float* pp = base;
            float gg = w00 * pp[i00] + w10 * pp[i10] + w01 * pp[i01] + w11 * pp[i11];
            a0 = fmaf(wgt, gg, a0);
        }
        {
            const float* pp = base + 4096;
            float gg = w00 * pp[i00] + w10 * pp[i10] + w01 * pp[i01] + w11 * pp[i11];
            a1 = fmaf(wgt, gg, a1);
        }
        {
            const float* pp = base + 8192;
            float gg = w00 * pp[i00] + w10 * pp[i10] + w01 * pp[i01] + w11 * pp[i11];
            a2 = fmaf(wgt, gg, a2);
        }
    }

    out[((size_t)(b * 3 + 0) * IMAGE_SIZE + h) * IMAGE_SIZE + w] = a0;
    out[((size_t)(b * 3 + 1) * IMAGE_SIZE + h) * IMAGE_SIZE + w] = a1;
    out[((size_t)(b * 3 + 2) * IMAGE_SIZE + h) * IMAGE_SIZE + w] = a2;
}

extern "C" void kernel_launch(void* const* d_in, const int* in_sizes, int n_in,
                              void* d_out, int out_size, void* d_ws, size_t ws_size,
                              hipStream_t stream) {
    const float* z_where   = (const float*)d_in[0];   // [4,32,4]
    const int*   z_present = (const int*)d_in[1];     // [4,32,1]
    const float* z_what    = (const float*)d_in[2];   // [4,32,64]
    const float* z_depth   = (const float*)d_in[3];   // [4,32,1]
    const float* w1 = (const float*)d_in[4];          // [64,512]
    const float* b1 = (const float*)d_in[5];          // [512]
    const float* w2 = (const float*)d_in[6];          // [512,12288]
    const float* b2 = (const float*)d_in[7];          // [12288]
    float* out = (float*)d_out;                       // [4,3,416,416] f32

    char* ws = (char*)d_ws;
    float* dec  = (float*)ws;                         // 6,291,456 B (compact slot)
    short* a_pk = (short*)(ws + 6291456);             //   131,072 B fragment-packed A
    float* pobj = (float*)(ws + 6422528);             //     4,096 B
    int*  pcnt  = (int*)(ws + 6426624);               //       256 B

    front_kernel<<<129, 512, 0, stream>>>(z_what, w1, b1, z_where, z_present,
                                          z_depth, a_pk, pobj, pcnt);
    mlp2_mfma<<<384, 256, 0, stream>>>(a_pk, w2, b2, dec);
    composite_kernel<<<dim3(13, 52, 4), 256, 0, stream>>>(dec, pobj, pcnt, out);
}